// Round 1
// baseline (169.619 us; speedup 1.0000x reference)
//
#include <hip/hip_runtime.h>

#define DIM_HID 65536
#define NKERS   500

// Kernel 1: y[row] = dot(W[row,:], x) + b[row]
// One block of 1024 threads per row. 65536 f32 = 16384 float4; 16 per thread.
__global__ __launch_bounds__(1024) void gemv_kernel(
    const float* __restrict__ W,
    const float* __restrict__ x,
    const float* __restrict__ b,
    float* __restrict__ y)
{
    const int row = blockIdx.x;
    const float4* __restrict__ Wrow =
        reinterpret_cast<const float4*>(W + (size_t)row * DIM_HID);
    const float4* __restrict__ xv = reinterpret_cast<const float4*>(x);

    const int t = threadIdx.x;
    float sum = 0.0f;
#pragma unroll
    for (int k = 0; k < 16; ++k) {
        const int idx = t + k * 1024;   // coalesced: consecutive lanes -> consecutive 16B
        float4 w = Wrow[idx];
        float4 v = xv[idx];
        sum = fmaf(w.x, v.x, sum);
        sum = fmaf(w.y, v.y, sum);
        sum = fmaf(w.z, v.z, sum);
        sum = fmaf(w.w, v.w, sum);
    }

    // wave (64-lane) butterfly reduce
#pragma unroll
    for (int off = 32; off > 0; off >>= 1)
        sum += __shfl_down(sum, off, 64);

    __shared__ float wsum[16];
    const int wave = t >> 6;
    const int lane = t & 63;
    if (lane == 0) wsum[wave] = sum;
    __syncthreads();

    if (t == 0) {
        float s = 0.0f;
#pragma unroll
        for (int w = 0; w < 16; ++w) s += wsum[w];
        y[row] = s + b[row];
    }
}

// Kernel 2: z[j] = sum_i y[i] * kernels[i][j] * (j < kwidths[i])
// kernels is only 1 MB (L2-resident). Consecutive lanes j read consecutive
// addresses per i -> coalesced. y[i]/kw[i] are wave-uniform scalar loads.
__global__ __launch_bounds__(256) void expand_kernel(
    const float* __restrict__ y,
    const float* __restrict__ kernels,
    const int* __restrict__ kw,
    float* __restrict__ z)
{
    const int j = blockIdx.x * blockDim.x + threadIdx.x;
    if (j >= NKERS) return;
    float acc = 0.0f;
    for (int i = 0; i < NKERS; ++i) {
        const float yi = y[i];
        const int   w  = kw[i];
        const float kv = kernels[i * NKERS + j];
        if (j < w) acc = fmaf(yi, kv, acc);
    }
    z[j] = acc;
}

extern "C" void kernel_launch(void* const* d_in, const int* in_sizes, int n_in,
                              void* d_out, int out_size, void* d_ws, size_t ws_size,
                              hipStream_t stream)
{
    const float* input   = (const float*)d_in[0];  // [65536]
    const float* weight  = (const float*)d_in[1];  // [500, 65536]
    const float* bias    = (const float*)d_in[2];  // [500]
    const float* kernels = (const float*)d_in[3];  // [500, 500]
    const int*   kwidths = (const int*)d_in[4];    // [500]
    float* z = (float*)d_out;                      // [500]
    float* y = (float*)d_ws;                       // [500] scratch

    gemv_kernel<<<NKERS, 1024, 0, stream>>>(weight, input, bias, y);
    expand_kernel<<<(NKERS + 255) / 256, 256, 0, stream>>>(y, kernels, kwidths, z);
}

// Round 2
// 33.620 us; speedup vs baseline: 5.0452x; 5.0452x over previous
//
#include <hip/hip_runtime.h>

#define DIM_HID 65536
#define NKERS   500

// Kernel 1: y[row] = dot(W[row,:], x) + b[row]
// One block of 1024 threads per row. 65536 f32 = 16384 float4; 16 per thread.
__global__ __launch_bounds__(1024) void gemv_kernel(
    const float* __restrict__ W,
    const float* __restrict__ x,
    const float* __restrict__ b,
    float* __restrict__ y)
{
    const int row = blockIdx.x;
    const float4* __restrict__ Wrow =
        reinterpret_cast<const float4*>(W + (size_t)row * DIM_HID);
    const float4* __restrict__ xv = reinterpret_cast<const float4*>(x);

    const int t = threadIdx.x;
    float sum = 0.0f;
#pragma unroll
    for (int k = 0; k < 16; ++k) {
        const int idx = t + k * 1024;   // coalesced: consecutive lanes -> consecutive 16B
        float4 w = Wrow[idx];
        float4 v = xv[idx];
        sum = fmaf(w.x, v.x, sum);
        sum = fmaf(w.y, v.y, sum);
        sum = fmaf(w.z, v.z, sum);
        sum = fmaf(w.w, v.w, sum);
    }

    // wave (64-lane) butterfly reduce
#pragma unroll
    for (int off = 32; off > 0; off >>= 1)
        sum += __shfl_down(sum, off, 64);

    __shared__ float wsum[16];
    const int wave = t >> 6;
    const int lane = t & 63;
    if (lane == 0) wsum[wave] = sum;
    __syncthreads();

    if (t == 0) {
        float s = 0.0f;
#pragma unroll
        for (int w = 0; w < 16; ++w) s += wsum[w];
        y[row] = s + b[row];
    }
}

// Kernel 2: z[j] = sum_i y[i] * kernels[i][j] * (j < kwidths[i])
// One block per j: 500 blocks x 256 threads = 2000 waves (latency-hidden).
// Each thread covers i = t and i = t+256 (2 independent loads, one wait),
// then wave shuffle-reduce + LDS cross-wave reduce. All data L2-resident.
__global__ __launch_bounds__(256) void expand_kernel(
    const float* __restrict__ y,
    const float* __restrict__ kernels,
    const int* __restrict__ kw,
    float* __restrict__ z)
{
    const int j = blockIdx.x;
    const int t = threadIdx.x;

    float acc = 0.0f;
#pragma unroll
    for (int k = 0; k < 2; ++k) {
        const int i = t + k * 256;
        if (i < NKERS) {
            const float yi = y[i];
            const int   w  = kw[i];
            const float kv = kernels[i * NKERS + j];
            if (j < w) acc = fmaf(yi, kv, acc);
        }
    }

#pragma unroll
    for (int off = 32; off > 0; off >>= 1)
        acc += __shfl_down(acc, off, 64);

    __shared__ float wsum[4];
    const int wave = t >> 6;
    const int lane = t & 63;
    if (lane == 0) wsum[wave] = acc;
    __syncthreads();

    if (t == 0)
        z[j] = (wsum[0] + wsum[1]) + (wsum[2] + wsum[3]);
}

extern "C" void kernel_launch(void* const* d_in, const int* in_sizes, int n_in,
                              void* d_out, int out_size, void* d_ws, size_t ws_size,
                              hipStream_t stream)
{
    const float* input   = (const float*)d_in[0];  // [65536]
    const float* weight  = (const float*)d_in[1];  // [500, 65536]
    const float* bias    = (const float*)d_in[2];  // [500]
    const float* kernels = (const float*)d_in[3];  // [500, 500]
    const int*   kwidths = (const int*)d_in[4];    // [500]
    float* z = (float*)d_out;                      // [500]
    float* y = (float*)d_ws;                       // [500] scratch

    gemv_kernel<<<NKERS, 1024, 0, stream>>>(weight, input, bias, y);
    expand_kernel<<<NKERS, 256, 0, stream>>>(y, kernels, kwidths, z);
}

// Round 4
// 32.322 us; speedup vs baseline: 5.2478x; 1.0401x over previous
//
#include <hip/hip_runtime.h>

#define DIM_HID 65536
#define NKERS   500
#define CHUNKS  16   // float4 chunks per thread per row (16384 float4 / 1024 threads)

typedef float f4 __attribute__((ext_vector_type(4)));  // native vector: legal for nontemporal builtins

// Kernel 1: y[r] = dot(W[r,:], x) + b[r], two rows per block.
// 250 blocks x 1024 threads, 1 block/CU (launch_bounds(1024,4) -> VGPR cap 512).
// Each thread issues 16 x-loads (L2) + 32 W-loads (HBM, nontemporal) into
// register arrays BEFORE consuming: ~48 loads in flight/wave x 16 waves/CU
// = ~12 KB in-flight per CU -> covers ~800cy HBM latency at full BW.
__global__ __launch_bounds__(1024, 4) void gemv_kernel(
    const float* __restrict__ W,
    const float* __restrict__ x,
    const float* __restrict__ b,
    float* __restrict__ y)
{
    const int r0 = blockIdx.x * 2;          // rows r0, r0+1
    const int t  = threadIdx.x;
    const f4* __restrict__ W0 =
        reinterpret_cast<const f4*>(W + (size_t)r0 * DIM_HID);
    const f4* __restrict__ W1 =
        reinterpret_cast<const f4*>(W + (size_t)(r0 + 1) * DIM_HID);
    const f4* __restrict__ xv = reinterpret_cast<const f4*>(x);

    f4 xb[CHUNKS], w0b[CHUNKS], w1b[CHUNKS];
#pragma unroll
    for (int k = 0; k < CHUNKS; ++k) {
        const int idx = t + k * 1024;       // coalesced across lanes
        w0b[k] = __builtin_nontemporal_load(&W0[idx]);
        w1b[k] = __builtin_nontemporal_load(&W1[idx]);
        xb[k]  = xv[idx];
    }

    float s0 = 0.0f, s1 = 0.0f;
#pragma unroll
    for (int k = 0; k < CHUNKS; ++k) {
        s0 = fmaf(w0b[k].x, xb[k].x, s0);
        s0 = fmaf(w0b[k].y, xb[k].y, s0);
        s0 = fmaf(w0b[k].z, xb[k].z, s0);
        s0 = fmaf(w0b[k].w, xb[k].w, s0);
        s1 = fmaf(w1b[k].x, xb[k].x, s1);
        s1 = fmaf(w1b[k].y, xb[k].y, s1);
        s1 = fmaf(w1b[k].z, xb[k].z, s1);
        s1 = fmaf(w1b[k].w, xb[k].w, s1);
    }

    // wave (64-lane) butterfly reduce, both accumulators
#pragma unroll
    for (int off = 32; off > 0; off >>= 1) {
        s0 += __shfl_down(s0, off, 64);
        s1 += __shfl_down(s1, off, 64);
    }

    __shared__ float wsum0[16], wsum1[16];
    const int wave = t >> 6;
    const int lane = t & 63;
    if (lane == 0) { wsum0[wave] = s0; wsum1[wave] = s1; }
    __syncthreads();

    if (t == 0) {
        float a = 0.0f, c = 0.0f;
#pragma unroll
        for (int w = 0; w < 16; ++w) { a += wsum0[w]; c += wsum1[w]; }
        y[r0]     = a + b[r0];
        y[r0 + 1] = c + b[r0 + 1];
    }
}

// Kernel 2: z[j] = sum_i y[i] * kernels[i][j] * (j < kwidths[i])
// One block per j: 500 blocks x 256 threads. All data L2-resident.
__global__ __launch_bounds__(256) void expand_kernel(
    const float* __restrict__ y,
    const float* __restrict__ kernels,
    const int* __restrict__ kw,
    float* __restrict__ z)
{
    const int j = blockIdx.x;
    const int t = threadIdx.x;

    float acc = 0.0f;
#pragma unroll
    for (int k = 0; k < 2; ++k) {
        const int i = t + k * 256;
        if (i < NKERS) {
            const float yi = y[i];
            const int   w  = kw[i];
            const float kv = kernels[i * NKERS + j];
            if (j < w) acc = fmaf(yi, kv, acc);
        }
    }

#pragma unroll
    for (int off = 32; off > 0; off >>= 1)
        acc += __shfl_down(acc, off, 64);

    __shared__ float wsum[4];
    const int wave = t >> 6;
    const int lane = t & 63;
    if (lane == 0) wsum[wave] = acc;
    __syncthreads();

    if (t == 0)
        z[j] = (wsum[0] + wsum[1]) + (wsum[2] + wsum[3]);
}

extern "C" void kernel_launch(void* const* d_in, const int* in_sizes, int n_in,
                              void* d_out, int out_size, void* d_ws, size_t ws_size,
                              hipStream_t stream)
{
    const float* input   = (const float*)d_in[0];  // [65536]
    const float* weight  = (const float*)d_in[1];  // [500, 65536]
    const float* bias    = (const float*)d_in[2];  // [500]
    const float* kernels = (const float*)d_in[3];  // [500, 500]
    const int*   kwidths = (const int*)d_in[4];    // [500]
    float* z = (float*)d_out;                      // [500]
    float* y = (float*)d_ws;                       // [500] scratch

    gemv_kernel<<<NKERS / 2, 1024, 0, stream>>>(weight, input, bias, y);
    expand_kernel<<<NKERS, 256, 0, stream>>>(y, kernels, kwidths, z);
}

// Round 5
// 29.762 us; speedup vs baseline: 5.6991x; 1.0860x over previous
//
#include <hip/hip_runtime.h>

#define DIM_HID 65536
#define NKERS   500
#define NQ      4                    // quarters per row
#define QCHUNK  (DIM_HID / NQ)       // 16384 floats per quarter
// 256 threads/block, QCHUNK/4 = 4096 float4 per block -> 16 float4/thread

typedef float f4 __attribute__((ext_vector_type(4)));

// Kernel 1: partial GEMV. Block (row, q) computes
//   ws[row*4+q] = dot(W[row, q*QCHUNK : (q+1)*QCHUNK], x[q*QCHUNK : ...])
// 2000 blocks x 256 threads, low VGPR -> 32 waves/CU (vs 16 before):
// doubles the outstanding-load pool feeding HBM.
__global__ __launch_bounds__(256) void gemv_part_kernel(
    const float* __restrict__ W,
    const float* __restrict__ x,
    float* __restrict__ ws)
{
    const int bid = blockIdx.x;          // 0..1999
    const int row = bid >> 2;
    const int q   = bid & 3;
    const int t   = threadIdx.x;

    const f4* __restrict__ Wq =
        reinterpret_cast<const f4*>(W + (size_t)row * DIM_HID + q * QCHUNK);
    const f4* __restrict__ xq =
        reinterpret_cast<const f4*>(x + q * QCHUNK);

    float s = 0.0f;
#pragma unroll 4
    for (int k = 0; k < 16; ++k) {
        const int idx = t + k * 256;                 // coalesced
        f4 w = __builtin_nontemporal_load(&Wq[idx]); // stream W once, keep x in L2
        f4 v = xq[idx];
        s = fmaf(w.x, v.x, s);
        s = fmaf(w.y, v.y, s);
        s = fmaf(w.z, v.z, s);
        s = fmaf(w.w, v.w, s);
    }

    // wave reduce
#pragma unroll
    for (int off = 32; off > 0; off >>= 1)
        s += __shfl_down(s, off, 64);

    __shared__ float wsum[4];
    const int wave = t >> 6;
    const int lane = t & 63;
    if (lane == 0) wsum[wave] = s;
    __syncthreads();

    if (t == 0)
        ws[bid] = (wsum[0] + wsum[1]) + (wsum[2] + wsum[3]);
}

// Kernel 2: z[j] = sum_i (ws[i*4..i*4+3]·1 + bias[i]) * kernels[i][j] * (j < kw[i])
// One block per j: 500 blocks x 256 threads. Everything L2-resident.
__global__ __launch_bounds__(256) void expand_kernel(
    const float* __restrict__ ws,
    const float* __restrict__ bias,
    const float* __restrict__ kernels,
    const int* __restrict__ kw,
    float* __restrict__ z)
{
    const int j = blockIdx.x;
    const int t = threadIdx.x;
    const f4* __restrict__ wsv = reinterpret_cast<const f4*>(ws);

    float acc = 0.0f;
#pragma unroll
    for (int k = 0; k < 2; ++k) {
        const int i = t + k * 256;
        if (i < NKERS) {
            f4 p = wsv[i];                              // the 4 partials of row i
            const float yi = ((p.x + p.y) + (p.z + p.w)) + bias[i];
            const int   w  = kw[i];
            const float kv = kernels[i * NKERS + j];
            if (j < w) acc = fmaf(yi, kv, acc);
        }
    }

#pragma unroll
    for (int off = 32; off > 0; off >>= 1)
        acc += __shfl_down(acc, off, 64);

    __shared__ float wsum[4];
    const int wave = t >> 6;
    const int lane = t & 63;
    if (lane == 0) wsum[wave] = acc;
    __syncthreads();

    if (t == 0)
        z[j] = (wsum[0] + wsum[1]) + (wsum[2] + wsum[3]);
}

extern "C" void kernel_launch(void* const* d_in, const int* in_sizes, int n_in,
                              void* d_out, int out_size, void* d_ws, size_t ws_size,
                              hipStream_t stream)
{
    const float* input   = (const float*)d_in[0];  // [65536]
    const float* weight  = (const float*)d_in[1];  // [500, 65536]
    const float* bias    = (const float*)d_in[2];  // [500]
    const float* kernels = (const float*)d_in[3];  // [500, 500]
    const int*   kwidths = (const int*)d_in[4];    // [500]
    float* z  = (float*)d_out;                     // [500]
    float* ws = (float*)d_ws;                      // [2000] partial dots

    gemv_part_kernel<<<NKERS * NQ, 256, 0, stream>>>(weight, input, ws);
    expand_kernel<<<NKERS, 256, 0, stream>>>(ws, bias, kernels, kwidths, z);
}